// Round 5
// baseline (29.165 us; speedup 1.0000x reference)
//
#include <hip/hip_runtime.h>

// Problem constants (match reference): B=128, T=512, DZ=512
#define BB 128
#define TT 512
#define DZ 512
#define RPB 128                         // rows (b,t pairs) per block
#define NBLOCKS ((BB * TT) / RPB)       // 512 blocks -> 2 per CU
// out[b,t,d] = init[b,d] + f[d] * prefixsum_{s<=t}(x[b,s])

typedef float f4_t __attribute__((ext_vector_type(4)));

__global__ __launch_bounds__(256, 4) void lts_kernel(
    const float* __restrict__ t_in,   // (B, T)
    const float* __restrict__ init,   // (B, DZ)
    const float* __restrict__ f,      // (DZ)
    float* __restrict__ out)          // (B, T, DZ)
{
    __shared__ float s[TT];

    const int tid = threadIdx.x;                 // 0..255
    const int g0  = blockIdx.x * RPB;            // global row base (b*T + t0)
    const int b   = g0 >> 9;                     // batch (T = 512)
    const int t0  = g0 & (TT - 1);               // local time base (mult of 128)

    // ---- Prologue: wave 0 computes the full inclusive scan of t_in[b, :] ----
    if (tid < 64) {
        const float* xb = t_in + b * TT + tid * 8;
        const f4_t a = *reinterpret_cast<const f4_t*>(xb);
        const f4_t c = *reinterpret_cast<const f4_t*>(xb + 4);
        const float v0 = a.x;
        const float v1 = v0 + a.y;
        const float v2 = v1 + a.z;
        const float v3 = v2 + a.w;
        const float v4 = v3 + c.x;
        const float v5 = v4 + c.y;
        const float v6 = v5 + c.z;
        const float v7 = v6 + c.w;
        float run = v7;
#pragma unroll
        for (int off = 1; off < 64; off <<= 1) {
            const float y = __shfl_up(run, off, 64);
            if (tid >= off) run += y;
        }
        const float excl = run - v7;             // exclusive prefix of lane totals
        f4_t o0, o1;
        o0.x = v0 + excl; o0.y = v1 + excl; o0.z = v2 + excl; o0.w = v3 + excl;
        o1.x = v4 + excl; o1.y = v5 + excl; o1.z = v6 + excl; o1.w = v7 + excl;
        *reinterpret_cast<f4_t*>(&s[tid * 8])     = o0;
        *reinterpret_cast<f4_t*>(&s[tid * 8 + 4]) = o1;
    }

    // ---- Fixed float4 column per thread across the full 512-float row ----
    const int q = tid & 127;                     // float4 column, 0..127
    const int h = tid >> 7;                      // row parity (wave-pair uniform)
    const int d = q * 4;

    const f4_t f4 = *reinterpret_cast<const f4_t*>(&f[d]);
    const f4_t i4 = *reinterpret_cast<const f4_t*>(&init[b * DZ + d]);

    __syncthreads();

    // ---- Stream 128 contiguous rows; each wave store = 1 KB contiguous ----
    // Single-variable A/B vs round 4: nontemporal store hint (evict-first).
    float* outp = out + ((size_t)(g0 + h) * DZ + d);
#pragma unroll 8
    for (int iter = 0; iter < RPB / 2; ++iter) {
        const float st = s[t0 + iter * 2 + h];   // wave-uniform LDS broadcast
        f4_t o;
        o.x = i4.x + f4.x * st;
        o.y = i4.y + f4.y * st;
        o.z = i4.z + f4.z * st;
        o.w = i4.w + f4.w * st;
        __builtin_nontemporal_store(o, reinterpret_cast<f4_t*>(outp));
        outp += 2 * DZ;
    }
}

extern "C" void kernel_launch(void* const* d_in, const int* in_sizes, int n_in,
                              void* d_out, int out_size, void* d_ws, size_t ws_size,
                              hipStream_t stream) {
    const float* t_in = (const float*)d_in[0];  // (B,T,1) -> (B,T)
    const float* init = (const float*)d_in[1];  // (B,DZ)
    const float* f    = (const float*)d_in[2];  // (1,DZ) -> (DZ)
    float* out        = (float*)d_out;          // (B,T,DZ)

    lts_kernel<<<dim3(NBLOCKS), dim3(256), 0, stream>>>(t_in, init, f, out);
}

// Round 6
// 28.815 us; speedup vs baseline: 1.0122x; 1.0122x over previous
//
#include <hip/hip_runtime.h>

// Problem constants (match reference): B=128, T=512, DZ=512
#define BB 128
#define TT 512
#define DZ 512
#define RPB 128                         // rows (b,t pairs) per block
#define NBLOCKS ((BB * TT) / RPB)       // 512 blocks -> 2 per CU
// out[b,t,d] = init[b,d] + f[d] * prefixsum_{s<=t}(x[b,s])
//
// Fully wave-independent: each of the 4 waves redundantly computes the whole
// 512-element scan, parks it in a PRIVATE LDS slice (same-wave lgkmcnt
// ordering, no __syncthreads anywhere), then streams 32 rows with 32 B/lane
// plain stores. nt stores proven -11% on this chip (rounds 3/5) - not used.

typedef float f4_t __attribute__((ext_vector_type(4)));

__global__ __launch_bounds__(256, 4) void lts_kernel(
    const float* __restrict__ t_in,   // (B, T)
    const float* __restrict__ init,   // (B, DZ)
    const float* __restrict__ f,      // (DZ)
    float* __restrict__ out)          // (B, T, DZ)
{
    __shared__ float s[4][TT];                   // 2 KB private per wave

    const int tid  = threadIdx.x;                // 0..255
    const int wave = tid >> 6;                   // 0..3
    const int lane = tid & 63;
    const int g0   = blockIdx.x * RPB;           // global row base (b*T + t0)
    const int b    = g0 >> 9;                    // batch (T = 512)
    const int t0   = g0 & (TT - 1);              // local time base (mult of 128)

    // ---- Issue the per-lane column loads first (latency overlap) ----
    const int d = lane * 8;                      // each lane owns 8 columns
    const f4_t fa = *reinterpret_cast<const f4_t*>(&f[d]);
    const f4_t fb = *reinterpret_cast<const f4_t*>(&f[d + 4]);
    const f4_t ia = *reinterpret_cast<const f4_t*>(&init[b * DZ + d]);
    const f4_t ib = *reinterpret_cast<const f4_t*>(&init[b * DZ + d + 4]);

    // ---- Per-wave redundant inclusive scan of t_in[b, :] ----
    const float* xb = t_in + b * TT + lane * 8;
    const f4_t a = *reinterpret_cast<const f4_t*>(xb);
    const f4_t c = *reinterpret_cast<const f4_t*>(xb + 4);
    const float v0 = a.x;
    const float v1 = v0 + a.y;
    const float v2 = v1 + a.z;
    const float v3 = v2 + a.w;
    const float v4 = v3 + c.x;
    const float v5 = v4 + c.y;
    const float v6 = v5 + c.z;
    const float v7 = v6 + c.w;
    float run = v7;
#pragma unroll
    for (int off = 1; off < 64; off <<= 1) {
        const float y = __shfl_up(run, off, 64);
        if (lane >= off) run += y;
    }
    const float excl = run - v7;                 // exclusive prefix of lane totals
    f4_t o0, o1;
    o0.x = v0 + excl; o0.y = v1 + excl; o0.z = v2 + excl; o0.w = v3 + excl;
    o1.x = v4 + excl; o1.y = v5 + excl; o1.z = v6 + excl; o1.w = v7 + excl;
    *reinterpret_cast<f4_t*>(&s[wave][lane * 8])     = o0;
    *reinterpret_cast<f4_t*>(&s[wave][lane * 8 + 4]) = o1;
    // no barrier: only this wave reads s[wave][*]; lgkmcnt orders write->read

    // ---- Stream 32 rows per wave; lane stores 32 B -> wave = 2 KB/row ----
    float* outp = out + ((size_t)(g0 + wave) * DZ + d);
#pragma unroll 8
    for (int iter = 0; iter < RPB / 4; ++iter) {
        const float st = s[wave][t0 + iter * 4 + wave];  // uniform broadcast
        f4_t oA, oB;
        oA.x = ia.x + fa.x * st;
        oA.y = ia.y + fa.y * st;
        oA.z = ia.z + fa.z * st;
        oA.w = ia.w + fa.w * st;
        oB.x = ib.x + fb.x * st;
        oB.y = ib.y + fb.y * st;
        oB.z = ib.z + fb.z * st;
        oB.w = ib.w + fb.w * st;
        *reinterpret_cast<f4_t*>(outp)     = oA;
        *reinterpret_cast<f4_t*>(outp + 4) = oB;
        outp += 4 * DZ;
    }
}

extern "C" void kernel_launch(void* const* d_in, const int* in_sizes, int n_in,
                              void* d_out, int out_size, void* d_ws, size_t ws_size,
                              hipStream_t stream) {
    const float* t_in = (const float*)d_in[0];  // (B,T,1) -> (B,T)
    const float* init = (const float*)d_in[1];  // (B,DZ)
    const float* f    = (const float*)d_in[2];  // (1,DZ) -> (DZ)
    float* out        = (float*)d_out;          // (B,T,DZ)

    lts_kernel<<<dim3(NBLOCKS), dim3(256), 0, stream>>>(t_in, init, f, out);
}

// Round 7
// 26.256 us; speedup vs baseline: 1.1108x; 1.0974x over previous
//
#include <hip/hip_runtime.h>

// Problem constants (match reference): B=128, T=512, DZ=512
#define BB 128
#define TT 512
#define DZ 512
#define RPB 128                         // rows (b,t pairs) per block
#define NBLOCKS ((BB * TT) / RPB)       // 512 blocks -> 2 per CU
// out[b,t,d] = init[b,d] + f[d] * prefixsum_{s<=t}(x[b,s])
//
// Final structure (best of 6 rounds, 26.3 us ~ 5.1 TB/s effective):
//  - wave 0 computes the 512-elem scan (reg-serial + shfl_up), parks in LDS
//  - one __syncthreads; then each wave streams rows with 1 KB-dense,
//    fully wave-contiguous 16 B/lane float4 stores
// A/B-tested and rejected: nontemporal stores (-11%), 32 B/lane strided
// stores (-9%), barrier-free readlane scan (neutral), 8 vs 2 blocks/CU
// (neutral). Residual vs 6.8 TB/s fill rate == launch + ramp overhead.

typedef float f4_t __attribute__((ext_vector_type(4)));

__global__ __launch_bounds__(256, 4) void lts_kernel(
    const float* __restrict__ t_in,   // (B, T)
    const float* __restrict__ init,   // (B, DZ)
    const float* __restrict__ f,      // (DZ)
    float* __restrict__ out)          // (B, T, DZ)
{
    __shared__ float s[TT];

    const int tid = threadIdx.x;                 // 0..255
    const int g0  = blockIdx.x * RPB;            // global row base (b*T + t0)
    const int b   = g0 >> 9;                     // batch (T = 512)
    const int t0  = g0 & (TT - 1);               // local time base (mult of 128)

    // ---- Prologue: wave 0 computes the full inclusive scan of t_in[b, :] ----
    if (tid < 64) {
        const float* xb = t_in + b * TT + tid * 8;
        const f4_t a = *reinterpret_cast<const f4_t*>(xb);
        const f4_t c = *reinterpret_cast<const f4_t*>(xb + 4);
        const float v0 = a.x;
        const float v1 = v0 + a.y;
        const float v2 = v1 + a.z;
        const float v3 = v2 + a.w;
        const float v4 = v3 + c.x;
        const float v5 = v4 + c.y;
        const float v6 = v5 + c.z;
        const float v7 = v6 + c.w;
        float run = v7;
#pragma unroll
        for (int off = 1; off < 64; off <<= 1) {
            const float y = __shfl_up(run, off, 64);
            if (tid >= off) run += y;
        }
        const float excl = run - v7;             // exclusive prefix of lane totals
        f4_t o0, o1;
        o0.x = v0 + excl; o0.y = v1 + excl; o0.z = v2 + excl; o0.w = v3 + excl;
        o1.x = v4 + excl; o1.y = v5 + excl; o1.z = v6 + excl; o1.w = v7 + excl;
        *reinterpret_cast<f4_t*>(&s[tid * 8])     = o0;
        *reinterpret_cast<f4_t*>(&s[tid * 8 + 4]) = o1;
    }

    // ---- Fixed float4 column per thread across the full 512-float row ----
    const int q = tid & 127;                     // float4 column, 0..127
    const int h = tid >> 7;                      // row parity (wave-pair uniform)
    const int d = q * 4;

    const f4_t f4 = *reinterpret_cast<const f4_t*>(&f[d]);
    const f4_t i4 = *reinterpret_cast<const f4_t*>(&init[b * DZ + d]);

    __syncthreads();

    // ---- Stream 128 contiguous rows; each wave store = 1 KB contiguous ----
    float* outp = out + ((size_t)(g0 + h) * DZ + d);
#pragma unroll 8
    for (int iter = 0; iter < RPB / 2; ++iter) {
        const float st = s[t0 + iter * 2 + h];   // wave-uniform LDS broadcast
        f4_t o;
        o.x = i4.x + f4.x * st;
        o.y = i4.y + f4.y * st;
        o.z = i4.z + f4.z * st;
        o.w = i4.w + f4.w * st;
        *reinterpret_cast<f4_t*>(outp) = o;
        outp += 2 * DZ;
    }
}

extern "C" void kernel_launch(void* const* d_in, const int* in_sizes, int n_in,
                              void* d_out, int out_size, void* d_ws, size_t ws_size,
                              hipStream_t stream) {
    const float* t_in = (const float*)d_in[0];  // (B,T,1) -> (B,T)
    const float* init = (const float*)d_in[1];  // (B,DZ)
    const float* f    = (const float*)d_in[2];  // (1,DZ) -> (DZ)
    float* out        = (float*)d_out;          // (B,T,DZ)

    lts_kernel<<<dim3(NBLOCKS), dim3(256), 0, stream>>>(t_in, init, f, out);
}